// Round 1
// baseline (526.173 us; speedup 1.0000x reference)
//
#include <hip/hip_runtime.h>
#include <cstdint>

#define B_ 32
#define N_ 64
#define H_ 128
#define S_ 100
#define C_ 16
#define SIGMA_ 0.5f

// output layout (floats): x_new | adj_new | assignments | x_emb | mask_new
#define OFF_XNEW 0
#define OFF_ADJN 262144
#define OFF_ASGN 393216
#define OFF_XEMB 598016
#define OFF_MSKN 860160

// ---- mask dtype sniffing: mask[0,0] is guaranteed true (counts >= 32) ----
__device__ __forceinline__ int read_mask_elem(const void* mp, int idx) {
    const unsigned int* u = (const unsigned int*)mp;
    const unsigned int w0 = u[0], w1 = u[1];
    if (w0 == 1u) {
        if (w1 == 1u) return ((const int*)mp)[idx] != 0;      // int32 (elem1 also true)
        return ((const int*)mp)[2 * idx] != 0;                 // int64
    }
    if (w0 == 0x3f800000u) return ((const float*)mp)[idx] != 0.0f;   // float32
    if (w0 == 0u) return ((const double*)mp)[idx] != 0.0;            // float64
    return ((const unsigned char*)mp)[idx] != 0;                     // bool bytes
}

// ================= Kernel A: 2-layer GCN, adj/mask bitmasks =================
__global__ __launch_bounds__(256) void gcn_kernel(
    const float* __restrict__ x, const float* __restrict__ adj,
    const void* __restrict__ maskp,
    const float* __restrict__ W1, const float* __restrict__ b1,
    const float* __restrict__ W2, const float* __restrict__ b2,
    float* __restrict__ out,
    unsigned long long* __restrict__ abits_ws,
    unsigned long long* __restrict__ mbits_ws)
{
    const int b = blockIdx.x;
    const int t = threadIdx.x;
    __shared__ float Xs[N_][130];   // padded strides to cut bank conflicts
    __shared__ float Hs[N_][130];
    __shared__ float An[N_][65];
    __shared__ float dsh[N_];
    __shared__ unsigned long long mb_sh;

    if (t < 64) {
        const int mv = read_mask_elem(maskp, b * N_ + t);
        const unsigned long long bal = __ballot(mv != 0);
        if (t == 0) { mb_sh = bal; mbits_ws[b] = bal; }
    }
    // adj -> An (diag forced to 1 for normalization) + adjacency bitmasks (ORIGINAL adj)
    for (int row = (t >> 6); row < N_; row += 4) {
        const int j = t & 63;
        const float v = adj[((size_t)b * N_ + row) * N_ + j];
        const unsigned long long bal = __ballot(v > 0.0f);
        if (j == 0) abits_ws[b * N_ + row] = bal;
        An[row][j] = (row == j) ? 1.0f : v;
    }
    __syncthreads();
    if (t < 64) {
        float s = 0.0f;
        for (int j = 0; j < N_; ++j) s += An[t][j];
        if (s < 1.0f) s = 1.0f;
        dsh[t] = 1.0f / sqrtf(s);
    }
    __syncthreads();
    for (int e = t; e < N_ * N_; e += 256) {
        const int i = e >> 6, j = e & 63;
        An[i][j] *= dsh[i] * dsh[j];
    }
    for (int e = t; e < N_ * H_; e += 256)
        Xs[e >> 7][e & 127] = x[(size_t)b * N_ * H_ + e];
    __syncthreads();

    const int ng = t & 15, kg = t >> 4;          // 4 nodes x 8 contiguous k per thread
    const unsigned long long mb = mb_sh;

    // ---- layer 1: Hs = Xs @ W1 ----
    {
        float acc[4][8] = {};
        for (int d = 0; d < H_; ++d) {
            float xv[4];
#pragma unroll
            for (int r = 0; r < 4; ++r) xv[r] = Xs[4 * ng + r][d];
            const float4 wa = *(const float4*)(W1 + d * H_ + 8 * kg);
            const float4 wb = *(const float4*)(W1 + d * H_ + 8 * kg + 4);
            const float wf[8] = {wa.x, wa.y, wa.z, wa.w, wb.x, wb.y, wb.z, wb.w};
#pragma unroll
            for (int j = 0; j < 8; ++j)
#pragma unroll
                for (int r = 0; r < 4; ++r) acc[r][j] += xv[r] * wf[j];
        }
#pragma unroll
        for (int r = 0; r < 4; ++r)
#pragma unroll
            for (int j = 0; j < 8; ++j) Hs[4 * ng + r][8 * kg + j] = acc[r][j];
    }
    __syncthreads();
    // ---- xe = relu(An @ Hs + b1) * mask -> Xs ----
    {
        float acc[4][8] = {};
        for (int j2 = 0; j2 < N_; ++j2) {
            float av[4];
#pragma unroll
            for (int r = 0; r < 4; ++r) av[r] = An[4 * ng + r][j2];
            float hv[8];
#pragma unroll
            for (int j = 0; j < 8; ++j) hv[j] = Hs[j2][8 * kg + j];
#pragma unroll
            for (int j = 0; j < 8; ++j)
#pragma unroll
                for (int r = 0; r < 4; ++r) acc[r][j] += av[r] * hv[j];
        }
        const float4 ba = *(const float4*)(b1 + 8 * kg);
        const float4 bb = *(const float4*)(b1 + 8 * kg + 4);
        const float bf[8] = {ba.x, ba.y, ba.z, ba.w, bb.x, bb.y, bb.z, bb.w};
#pragma unroll
        for (int r = 0; r < 4; ++r) {
            const int i = 4 * ng + r;
            const float m = ((mb >> i) & 1ull) ? 1.0f : 0.0f;
#pragma unroll
            for (int j = 0; j < 8; ++j)
                Xs[i][8 * kg + j] = fmaxf(acc[r][j] + bf[j], 0.0f) * m;
        }
    }
    __syncthreads();
    // ---- layer 2: Hs = Xs @ W2 ----
    {
        float acc[4][8] = {};
        for (int d = 0; d < H_; ++d) {
            float xv[4];
#pragma unroll
            for (int r = 0; r < 4; ++r) xv[r] = Xs[4 * ng + r][d];
            const float4 wa = *(const float4*)(W2 + d * H_ + 8 * kg);
            const float4 wb = *(const float4*)(W2 + d * H_ + 8 * kg + 4);
            const float wf[8] = {wa.x, wa.y, wa.z, wa.w, wb.x, wb.y, wb.z, wb.w};
#pragma unroll
            for (int j = 0; j < 8; ++j)
#pragma unroll
                for (int r = 0; r < 4; ++r) acc[r][j] += xv[r] * wf[j];
        }
        __syncthreads();
#pragma unroll
        for (int r = 0; r < 4; ++r)
#pragma unroll
            for (int j = 0; j < 8; ++j) Hs[4 * ng + r][8 * kg + j] = acc[r][j];
    }
    __syncthreads();
    // ---- x_emb = relu(An @ Hs + b2) * mask -> global ----
    {
        float acc[4][8] = {};
        for (int j2 = 0; j2 < N_; ++j2) {
            float av[4];
#pragma unroll
            for (int r = 0; r < 4; ++r) av[r] = An[4 * ng + r][j2];
            float hv[8];
#pragma unroll
            for (int j = 0; j < 8; ++j) hv[j] = Hs[j2][8 * kg + j];
#pragma unroll
            for (int j = 0; j < 8; ++j)
#pragma unroll
                for (int r = 0; r < 4; ++r) acc[r][j] += av[r] * hv[j];
        }
        const float4 ba = *(const float4*)(b2 + 8 * kg);
        const float4 bb = *(const float4*)(b2 + 8 * kg + 4);
        const float bf[8] = {ba.x, ba.y, ba.z, ba.w, bb.x, bb.y, bb.z, bb.w};
#pragma unroll
        for (int r = 0; r < 4; ++r) {
            const int i = 4 * ng + r;
            const float m = ((mb >> i) & 1ull) ? 1.0f : 0.0f;
#pragma unroll
            for (int j = 0; j < 8; ++j)
                out[OFF_XEMB + (size_t)b * N_ * H_ + i * H_ + 8 * kg + j] =
                    fmaxf(acc[r][j] + bf[j], 0.0f) * m;
        }
    }
}

// ========= Kernel B: per (sample,batch) — MLP, argmax, components, pooling =========
__global__ __launch_bounds__(256) void sample_kernel(
    const float* __restrict__ noise,
    const float* __restrict__ cW1, const float* __restrict__ cb1,
    const float* __restrict__ cW2, const float* __restrict__ cb2,
    const unsigned long long* __restrict__ abits_ws,
    const unsigned long long* __restrict__ mbits_ws,
    float* __restrict__ out, int* __restrict__ gNcl)
{
    const int sb = blockIdx.x;
    const int b  = sb & (B_ - 1);
    const int t  = threadIdx.x;
    __shared__ float xa[N_ * H_];    // x_all, chunk-XOR-swizzled
    __shared__ float hid[N_ * H_];   // hidden, swizzled; later reused as cluster sums
    __shared__ int   concepts[N_];
    __shared__ int   a_lds[N_];
    __shared__ unsigned long long reachL[N_];
    __shared__ unsigned long long cmS[N_];
    __shared__ unsigned long long roS[N_];
    __shared__ unsigned long long abS[N_];
    __shared__ unsigned int presLo, presHi;

    const unsigned long long mb = mbits_ws[b];
    if (t < 64) abS[t] = abits_ws[b * N_ + t];
    if (t == 0) { presLo = 0u; presHi = 0u; }

    // stage xa = x_emb[b] + 0.5*noise[sb]  (swizzle: chunk cc of row i at cc ^ ((i>>2)&7))
    {
        const float4* e4 = (const float4*)(out + OFF_XEMB + (size_t)b * N_ * H_);
        const float4* n4 = (const float4*)(noise + (size_t)sb * N_ * H_);
        float4* x4 = (float4*)xa;
        for (int idx = t; idx < N_ * 32; idx += 256) {
            const int i = idx >> 5, cc = idx & 31;
            const float4 ev = e4[idx], nv = n4[idx];
            float4 v;
            v.x = ev.x + SIGMA_ * nv.x;  v.y = ev.y + SIGMA_ * nv.y;
            v.z = ev.z + SIGMA_ * nv.z;  v.w = ev.w + SIGMA_ * nv.w;
            x4[i * 32 + (cc ^ ((i >> 2) & 7))] = v;
        }
    }
    __syncthreads();

    // ---- hidden = relu(xa @ cW1 + cb1), cW1 streamed from global ----
    {
        const int ng = t & 15, kg = t >> 4;     // 4 nodes x 8 contiguous k
        float acc[4][8] = {};
        const float4* x4 = (const float4*)xa;
        for (int cc = 0; cc < 32; ++cc) {
            float xv[4][4];
#pragma unroll
            for (int r = 0; r < 4; ++r) {
                const float4 tmp = x4[(4 * ng + r) * 32 + (cc ^ (ng & 7))];
                xv[r][0] = tmp.x; xv[r][1] = tmp.y; xv[r][2] = tmp.z; xv[r][3] = tmp.w;
            }
#pragma unroll
            for (int dd = 0; dd < 4; ++dd) {
                const int d = cc * 4 + dd;
                const float4 wa = *(const float4*)(cW1 + d * H_ + 8 * kg);
                const float4 wb = *(const float4*)(cW1 + d * H_ + 8 * kg + 4);
                const float wf[8] = {wa.x, wa.y, wa.z, wa.w, wb.x, wb.y, wb.z, wb.w};
#pragma unroll
                for (int j = 0; j < 8; ++j)
#pragma unroll
                    for (int r = 0; r < 4; ++r) acc[r][j] += xv[r][dd] * wf[j];
            }
        }
        const float4 ba = *(const float4*)(cb1 + 8 * kg);
        const float4 bb = *(const float4*)(cb1 + 8 * kg + 4);
        const float bf[8] = {ba.x, ba.y, ba.z, ba.w, bb.x, bb.y, bb.z, bb.w};
#pragma unroll
        for (int r = 0; r < 4; ++r) {
            const int i = 4 * ng + r;
            const int swz = ng & 7;             // == (i>>2)&7
            float4 o0, o1;
            o0.x = fmaxf(acc[r][0] + bf[0], 0.f); o0.y = fmaxf(acc[r][1] + bf[1], 0.f);
            o0.z = fmaxf(acc[r][2] + bf[2], 0.f); o0.w = fmaxf(acc[r][3] + bf[3], 0.f);
            o1.x = fmaxf(acc[r][4] + bf[4], 0.f); o1.y = fmaxf(acc[r][5] + bf[5], 0.f);
            o1.z = fmaxf(acc[r][6] + bf[6], 0.f); o1.w = fmaxf(acc[r][7] + bf[7], 0.f);
            *(float4*)&hid[i * H_ + (((2 * kg)     ^ swz) << 2)] = o0;
            *(float4*)&hid[i * H_ + (((2 * kg + 1) ^ swz) << 2)] = o1;
        }
    }
    __syncthreads();

    // ---- logits + argmax -> concepts (split-K over 4 lanes per node) ----
    {
        const int node = t >> 2, q = t & 3;
        const int h = (node >> 2) & 7;
        float acc[C_] = {};
        for (int kk = 0; kk < 32; ++kk) {
            const int k = 4 * kk + q;
            const float hv = hid[node * H_ + ((kk ^ h) << 2) + q];
            const float4 w0 = *(const float4*)(cW2 + k * C_);
            const float4 w1 = *(const float4*)(cW2 + k * C_ + 4);
            const float4 w2 = *(const float4*)(cW2 + k * C_ + 8);
            const float4 w3 = *(const float4*)(cW2 + k * C_ + 12);
            acc[0]  += hv * w0.x; acc[1]  += hv * w0.y; acc[2]  += hv * w0.z; acc[3]  += hv * w0.w;
            acc[4]  += hv * w1.x; acc[5]  += hv * w1.y; acc[6]  += hv * w1.z; acc[7]  += hv * w1.w;
            acc[8]  += hv * w2.x; acc[9]  += hv * w2.y; acc[10] += hv * w2.z; acc[11] += hv * w2.w;
            acc[12] += hv * w3.x; acc[13] += hv * w3.y; acc[14] += hv * w3.z; acc[15] += hv * w3.w;
        }
#pragma unroll
        for (int c = 0; c < C_; ++c) {
            acc[c] += __shfl_xor(acc[c], 1);
            acc[c] += __shfl_xor(acc[c], 2);
        }
        if (q == 0) {
            float best = acc[0] + cb2[0]; int bi = 0;
#pragma unroll
            for (int c = 1; c < C_; ++c) {
                const float v = acc[c] + cb2[c];
                if (v > best) { best = v; bi = c; }   // strict >: ties keep lowest index (jnp.argmax)
            }
            concepts[node] = bi;
        }
    }
    __syncthreads();

    // ---- connected components on same-concept masked subgraph via bitset closure ----
    unsigned long long reach = 0ull;
    int masked_i = 0;
    if (t < 64) {
        masked_i = (int)((mb >> t) & 1ull);
        if (masked_i) {
            const int ci = concepts[t];
            unsigned long long mm = abS[t] & mb;
            unsigned long long em = 0ull;
            while (mm) {
                const int j = __builtin_ctzll(mm);
                if (concepts[j] == ci) em |= (1ull << j);
                mm &= mm - 1;
            }
            reach = em | (1ull << t);
        }
        reachL[t] = reach;
    }
    __syncthreads();
#pragma unroll 1
    for (int it = 0; it < 6; ++it) {             // 2^6 = 64 >= max path length
        unsigned long long r = reach;
        if (masked_i) {
            unsigned long long mm = reach;
            while (mm) {
                const int j = __builtin_ctzll(mm);
                r |= reachL[j];
                mm &= mm - 1;
            }
        }
        __syncthreads();
        if (t < 64) reachL[t] = r;
        reach = r;
        __syncthreads();
    }
    int root = 0;
    if (masked_i) {
        root = __builtin_ctzll(reach);           // min node index in component
        if (root < 32) atomicOr(&presLo, 1u << root);
        else           atomicOr(&presHi, 1u << (root - 32));
    }
    __syncthreads();
    const unsigned long long present =
        ((unsigned long long)presHi << 32) | (unsigned long long)presLo;
    const int ncl = __popcll(present);
    if (t < 64) {
        int a_i = 0;
        if (masked_i) {
            a_i = __popcll(present & ((1ull << root) - 1ull)) + 1;   // compact 1-based id
            if (root == t) {                     // component representative
                cmS[a_i - 1] = reach;            // member bitmask
                unsigned long long ro = 0ull, mm = reach;
                while (mm) { const int j = __builtin_ctzll(mm); ro |= abS[j]; mm &= mm - 1; }
                roS[a_i - 1] = ro;               // OR of adjacency rows of members
            }
        }
        a_lds[t] = a_i;
        out[OFF_ASGN + (size_t)sb * N_ + t] = (float)a_i;
    }
    __syncthreads();

    // ---- adj_new: count (0/1) connections between clusters ----
    {
        int* adjCnt = (int*)out + OFF_ADJN;
        for (int idx = t; idx < N_ * N_; idx += 256) {
            const int c1 = idx >> 6, c2 = idx & 63;
            if (c1 < ncl && c2 < ncl && (roS[c1] & cmS[c2]))
                atomicAdd(&adjCnt[b * N_ * N_ + idx], 1);
        }
    }
    // ---- x_new: per-block cluster sums in LDS (reuse hid), then global atomics ----
    for (int e = t; e < N_ * H_; e += 256) hid[e] = 0.0f;
    __syncthreads();
    for (int e = t; e < N_ * H_; e += 256) {
        const int i = e >> 7, d = e & 127;
        const int a = a_lds[i];
        if (a) {
            const float v = xa[i * H_ + ((((d >> 2) ^ ((i >> 2) & 7)) << 2) | (d & 3))];
            atomicAdd(&hid[(a - 1) * H_ + d], v);
        }
    }
    __syncthreads();
    for (int e = t; e < ncl * H_; e += 256)
        atomicAdd(&out[OFF_XNEW + (size_t)b * N_ * H_ + e], hid[e]);
    if (t == 0) atomicMax(&gNcl[b], ncl);
}

// ================= Kernel C: finalize (means, mask_new) =================
__global__ __launch_bounds__(256) void finalize_kernel(
    float* __restrict__ out, const int* __restrict__ gNcl)
{
    const int idx = blockIdx.x * 256 + threadIdx.x;
    if (idx < OFF_ADJN) {
        out[idx] = out[idx] / 100.0f;                     // x_new mean over S=100
    } else if (idx < OFF_ASGN) {
        const int c = ((const int*)out)[idx];             // adj counts accumulated as int
        out[idx] = (float)c / 100.0f;
    } else {
        const int m = idx - OFF_ASGN;
        if (m < B_ * N_) {
            const int bb = m >> 6, k = m & 63;
            out[OFF_MSKN + m] = (k < gNcl[bb]) ? 1.0f : 0.0f;
        }
    }
}

extern "C" void kernel_launch(void* const* d_in, const int* in_sizes, int n_in,
                              void* d_out, int out_size, void* d_ws, size_t ws_size,
                              hipStream_t stream) {
    (void)in_sizes; (void)n_in; (void)out_size; (void)ws_size;
    const float* x    = (const float*)d_in[0];
    const float* adj  = (const float*)d_in[1];
    const void*  mskp = d_in[2];
    const float* W1   = (const float*)d_in[3];
    const float* b1   = (const float*)d_in[4];
    const float* W2   = (const float*)d_in[5];
    const float* b2   = (const float*)d_in[6];
    const float* cW1  = (const float*)d_in[7];
    const float* cb1  = (const float*)d_in[8];
    const float* cW2  = (const float*)d_in[9];
    const float* cb2  = (const float*)d_in[10];
    const float* noise = (const float*)d_in[11];
    float* out = (float*)d_out;

    // ws: [0,256) gNcl (32 ints), [256, 256+16384) adjacency bitmasks, then mask bitmasks
    int* gNcl = (int*)d_ws;
    unsigned long long* abits_ws = (unsigned long long*)((char*)d_ws + 256);
    unsigned long long* mbits_ws = (unsigned long long*)((char*)d_ws + 256 + 16384);

    hipMemsetAsync(d_out, 0, (size_t)OFF_ASGN * sizeof(float), stream); // zero x_new + adj_new accumulators
    hipMemsetAsync(d_ws, 0, 256, stream);                               // zero gNcl

    gcn_kernel<<<B_, 256, 0, stream>>>(x, adj, mskp, W1, b1, W2, b2,
                                       out, abits_ws, mbits_ws);
    sample_kernel<<<S_ * B_, 256, 0, stream>>>(noise, cW1, cb1, cW2, cb2,
                                               abits_ws, mbits_ws, out, gNcl);
    finalize_kernel<<<(OFF_ASGN + B_ * N_ + 255) / 256, 256, 0, stream>>>(out, gNcl);
}